// Round 1
// 62.003 us; speedup vs baseline: 1.0179x; 1.0179x over previous
//
#include <hip/hip_runtime.h>

#define OUT_HW 7
#define BINS   (OUT_HW * OUT_HW)  // 49
#define NCH    256
#define NB     2                  // batch size (fixed by problem)
#define FH     38
#define FW     38
#define PLANE  (FH * FW)          // 1444 floats = 5776 B
#define PLANE4 (PLANE / 4)        // 361 float4
#define PLANE_PAD4 364            // padded plane stride, float4
#define PLANE_PADF (PLANE_PAD4 * 4)  // 1456 floats
#define RPB    8                  // rois per block

// ===== SACRED boundary math (bit-exact vs checker, R17 absmax=0.0) =====
// XLA-CPU-fastmath emulation: span/7 -> span * rn32(1/7) (0x3E124925),
// oh*bin + start contracted to a single fmaf. Do not alter operations,
// order, or precision.
// =======================================================================

// Restructure vs previous round: instead of one block per 4 (roi,channel)
// planes (which re-staged each 5776B plane once per roi -> 94.6 MB global
// reads for a 2.96 MB feature tensor), each block now owns one channel and
// a group of RPB rois, stages BOTH batch planes of that channel once
// (11.6 KB LDS), and computes RPB*49 outputs from them. 4x less global
// traffic, half the blocks.
__global__ __launch_bounds__(256) void roi_pool_kernel(
    const float* __restrict__ feat,
    const int*   __restrict__ rois,
    float*       __restrict__ out)
{
    __shared__ float4 lds4[NB * PLANE_PAD4];   // 11,648 B
    __shared__ int    ldsroi[RPB * 5];

    int tid = threadIdx.x;
    int c   = blockIdx.x & (NCH - 1);   // channel
    int g   = blockIdx.x >> 8;          // roi group
    int r0  = g * RPB;

    // stage this block's roi records (40 ints)
    if (tid < RPB * 5) ldsroi[tid] = rois[r0 * 5 + tid];

    // stage both batch planes of channel c (coalesced float4)
    const float4* src0 = (const float4*)(feat + (size_t)c * PLANE);
    const float4* src1 = (const float4*)(feat + ((size_t)NCH + c) * PLANE);
    #pragma unroll
    for (int i = 0; i < 2; ++i) {
        int j = tid + i * 256;
        if (j < PLANE4) {
            lds4[j]              = src0[j];
            lds4[PLANE_PAD4 + j] = src1[j];
        }
    }
    __syncthreads();

    const float* lf = (const float*)lds4;

    // 392 outputs / 256 threads -> 2 rounds, second predicated
    #pragma unroll
    for (int o = tid; o < RPB * BINS; o += 256) {
        int lr   = o / BINS;            // local roi 0..7
        int bin  = o - lr * BINS;       // 0..48
        int oh   = bin / OUT_HW;
        int ow   = bin - oh * OUT_HW;
        const int* roi = &ldsroi[lr * 5];
        int ridx = roi[0];

        // ---- SACRED window computation (identical ops to passing R17) ----
        float sw = (float)roi[1] * 0.0625f;
        float sh = (float)roi[2] * 0.0625f;
        float ew = (float)roi[3] * 0.0625f;
        float eh = (float)roi[4] * 0.0625f;

        const float C7 = __uint_as_float(0x3E124925u);   // rn32(1/7)
        float bw = __fmul_rn(fmaxf(ew - sw, 1.0f), C7);
        float bh = __fmul_rn(fmaxf(eh - sh, 1.0f), C7);

        int hs = (int)floorf(fmaf((float)oh,       bh, sh));
        int he = (int)ceilf (fmaf((float)(oh + 1), bh, sh));
        int ws = (int)floorf(fmaf((float)ow,       bw, sw));
        int we = (int)ceilf (fmaf((float)(ow + 1), bw, sw));

        hs = min(max(hs, 0), FH);
        he = min(max(he, 0), FH);
        ws = min(max(ws, 0), FW);
        we = min(max(we, 0), FW);
        // ------------------------------------------------------------------

        float m = 0.0f;
        if (hs < he && ws < we) {
            m = -INFINITY;
            const float* pl = lf + ridx * PLANE_PADF;
            for (int h = hs; h < he; ++h) {
                const float* row = pl + h * FW;
                for (int w = ws; w < we; ++w) {
                    m = fmaxf(m, row[w]);
                }
            }
        }
        out[((size_t)((r0 + lr) * NCH + c)) * BINS + bin] = m;
    }
}

extern "C" void kernel_launch(void* const* d_in, const int* in_sizes, int n_in,
                              void* d_out, int out_size, void* d_ws, size_t ws_size,
                              hipStream_t stream) {
    const float* feat = (const float*)d_in[0];
    const int*   rois = (const int*)d_in[1];
    float*       out  = (float*)d_out;

    // out_size = n_rois * 256 * 49 elements
    int n_rois = out_size / (BINS * NCH);      // 64
    int groups = n_rois / RPB;                 // 8
    roi_pool_kernel<<<dim3(NCH * groups), 256, 0, stream>>>(feat, rois, out);
}